// Round 22
// baseline (129.137 us; speedup 1.0000x reference)
//
#include <hip/hip_runtime.h>
#include <hip/hip_bf16.h>
#include <stdint.h>

// MultiHeadCrossAttention: B=8, C=512, H=W=32 (S=1024), nh=8, d=64.
// R22: transpose+cast FUSED into GEMM staging (removes the 24MB Xt intermediate
//      = 48MB HBM roundtrip + one launch). X-sourced operand (A for Q/K, B for V)
//      reg-staged from f32: 8x global_load_dwordx4 / lane (coalesced per c-row),
//      16x v_cvt_pk_bf16_f32, 4x ds_write_b128 into 3-bit-XOR-swizzled tile
//      (reads use attn-proven 8*((kk*4+lg)^(lm&7))); W operand keeps
//      global_load_lds linear. X loads pipelined 1 k-step ahead (vA/vB named sets).
//      Grid: batch = XCD (768 = 8x96 bijective) -> X slice 2MB L2-resident across
//      x4 tile re-reads. attn reverted to measured-best R18 (KVBLK=128).
//      R21 post-mortem: de-phasing failed (67.29 vs R18 65.18); attn residual
//      theories exhausted -> attack prep+gemm HBM roundtrip instead.

typedef __attribute__((ext_vector_type(4))) float f32x4;
typedef __attribute__((ext_vector_type(8))) short short8;
typedef __attribute__((ext_vector_type(4))) unsigned int u32x4;

#define GLB_AS(p) ((const __attribute__((address_space(1))) void*)(p))
#define LDS_AS(p) ((__attribute__((address_space(3))) void*)(p))

__device__ __forceinline__ unsigned short f2b(float f) {
  unsigned int x = __builtin_bit_cast(unsigned int, f);
  x = (x + 0x7FFFu + ((x >> 16) & 1u)) >> 16;   // RNE
  return (unsigned short)x;
}

__device__ __forceinline__ float exp2_hw(float x) {
  float r;
  asm("v_exp_f32 %0, %1" : "=v"(r) : "v"(x));
  return r;
}

__device__ __forceinline__ unsigned int cvtpk(float lo, float hi) {
  unsigned int r;
  asm("v_cvt_pk_bf16_f32 %0, %1, %2" : "=v"(r) : "v"(lo), "v"(hi));
  return r;
}

__device__ __forceinline__ f32x4 mfma16(short8 a, short8 b, f32x4 c) {
  return __builtin_amdgcn_mfma_f32_16x16x32_bf16(a, b, c, 0, 0, 0);
}

// ---- prep: 3 weights f32 -> bf16, one small launch ----
__global__ __launch_bounds__(256) void cast_w3(const float* __restrict__ wq,
                                               const float* __restrict__ wk,
                                               const float* __restrict__ wv,
                                               unsigned short* __restrict__ O) {
  const int y = blockIdx.y;
  const float* W = (y == 0) ? wq : ((y == 1) ? wk : wv);
  int i = blockIdx.x * 256 + threadIdx.x;   // 65536 float4 per weight
  float4 v = ((const float4*)W)[i];
  uint2 u;
  u.x = (unsigned)f2b(v.x) | ((unsigned)f2b(v.y) << 16);
  u.y = (unsigned)f2b(v.z) | ((unsigned)f2b(v.w) << 16);
  ((uint2*)(O + (long)y * 262144))[i] = u;
}

// ---- fused projection GEMM: transpose+cast of X folded into staging ----
// bid: batch = bid&7 (pinned to XCD), j = bid>>3: kind = j>>5 (0 Q,1 K,2 V), tile = j&31.
// Q/K: C[s,c] = (X^T . W^T + b) [*scale]; A(X-sourced, swizzled), B=W (gl_lds linear).
// V:   C[c,t] = Wv . X^T + bv;   A=Wv (gl_lds linear), B(X-sourced, swizzled).
__global__ void gemm_proj(const float* __restrict__ Xq, const float* __restrict__ Xk,
                          const float* __restrict__ Xv, const unsigned short* __restrict__ W3,
                          unsigned short* __restrict__ QKV, const float* __restrict__ bq,
                          const float* __restrict__ bk, const float* __restrict__ bv) {
  __shared__ __align__(16) unsigned short lA[128 * 64];
  __shared__ __align__(16) unsigned short lB[128 * 64];
  const long SC = 1024L * 512;
  const int bid = blockIdx.x;
  const int batch = bid & 7;
  const int j = bid >> 3;
  const int kind = j >> 5, tile = j & 31;
  const bool aFromX = (kind < 2);
  const float* Xsrc = ((kind == 0) ? Xq : ((kind == 1) ? Xk : Xv)) + (long)batch * 512 * 1024;
  const unsigned short* Wsrc = W3 + (long)kind * 262144;
  unsigned short* Cb;
  const float* bias;
  int m0, n0, N, biasN, r0x, wrow0;
  float scale = 1.0f;
  if (aFromX) {
    m0 = (tile >> 2) * 128; n0 = (tile & 3) * 128; N = 512; biasN = 1;
    r0x = m0; wrow0 = n0;
    Cb = QKV + ((long)kind * 8 + batch) * SC;
    bias = kind ? bk : bq;
    if (kind == 0) scale = 0.18033688011112042f;  // 0.125 * log2(e)
  } else {
    m0 = (tile >> 3) * 128; n0 = (tile & 7) * 128; N = 1024; biasN = 0;
    r0x = n0; wrow0 = m0;
    Cb = QKV + (16L + batch) * SC;
    bias = bv;
  }
  unsigned short* lX = aFromX ? lA : lB;   // X-sourced tile (swizzled)
  unsigned short* lW = aFromX ? lB : lA;   // W tile (linear)
  const int tid = threadIdx.x, lane = tid & 63, wid = tid >> 6;
  const int wr = wid >> 1, wc = wid & 1;
  const int lm = lane & 15, lg = lane >> 4;
  const int aX = aFromX ? (lm & 7) : 0;
  const int bX = aFromX ? 0 : (lm & 7);
  // X staging geometry: wave w rows [w*32, w*32+32); oct = c-octet, qd = row-quad
  const int oct = lane & 7, qd = lane >> 3;
  const int xrow = wid * 32 + qd * 4;

  auto loadX = [&](f32x4 (&v)[8], int k0) {
#pragma unroll
    for (int e = 0; e < 8; ++e)
      v[e] = *(const f32x4*)&Xsrc[(long)(k0 + oct * 8 + e) * 1024 + r0x + xrow];
  };
  auto writeX = [&](f32x4 (&v)[8]) {
#pragma unroll
    for (int jj = 0; jj < 4; ++jj) {
      int row = xrow + jj;
      u32x4 pw;
      pw[0] = cvtpk(v[0][jj], v[1][jj]);
      pw[1] = cvtpk(v[2][jj], v[3][jj]);
      pw[2] = cvtpk(v[4][jj], v[5][jj]);
      pw[3] = cvtpk(v[6][jj], v[7][jj]);
      *(u32x4*)&lX[row * 64 + 8 * (oct ^ (row & 7))] = pw;
    }
  };
  auto stageW = [&](int k0) {
#pragma unroll
    for (int ch = wid; ch < 16; ch += 4) {
      int e = ch * 512 + lane * 8;
      int r = e >> 6, cc = e & 63;
      __builtin_amdgcn_global_load_lds(GLB_AS(Wsrc + (long)(wrow0 + r) * 512 + k0 + cc),
                                       LDS_AS(lW + ch * 512), 16, 0, 0);
    }
  };

  f32x4 acc[4][4] = {};
  auto compute = [&]() {
#pragma unroll
    for (int kk = 0; kk < 2; ++kk) {
      short8 af[4], bf[4];
#pragma unroll
      for (int i = 0; i < 4; ++i)
        af[i] = *(const short8*)&lA[(wr * 64 + i * 16 + lm) * 64 + 8 * ((kk * 4 + lg) ^ aX)];
#pragma unroll
      for (int jj = 0; jj < 4; ++jj)
        bf[jj] = *(const short8*)&lB[(wc * 64 + jj * 16 + lm) * 64 + 8 * ((kk * 4 + lg) ^ bX)];
#pragma unroll
      for (int i = 0; i < 4; ++i)
#pragma unroll
        for (int jj = 0; jj < 4; ++jj)
          acc[i][jj] = mfma16(af[i], bf[jj], acc[i][jj]);
    }
  };

  f32x4 vA[8], vB[8];
  loadX(vA, 0);
#pragma unroll 1
  for (int kq = 0; kq < 8; kq += 2) {
    stageW(kq * 64);
    loadX(vB, kq * 64 + 64);          // next k-tile, regs only (no LDS hazard)
    writeX(vA);
    __syncthreads();
    compute();
    __syncthreads();
    stageW(kq * 64 + 64);
    if (kq < 6) loadX(vA, kq * 64 + 128);
    writeX(vB);
    __syncthreads();
    compute();
    __syncthreads();
  }

#pragma unroll
  for (int i = 0; i < 4; ++i)
#pragma unroll
    for (int jj = 0; jj < 4; ++jj)
#pragma unroll
      for (int r = 0; r < 4; ++r) {
        int m = m0 + wr * 64 + i * 16 + lg * 4 + r;
        int n = n0 + wc * 64 + jj * 16 + lm;
        float bvv = biasN ? bias[n] : bias[m];
        Cb[(long)m * N + n] = f2b((acc[i][jj][r] + bvv) * scale);
      }
}

// ---- fused flash attention: KVBLK=128, LDS-staged K/V (swizzled), in-register P ----
// (R18 version, measured best.) Qt[b,s,c] pre-scaled by 0.125*log2e; Kt[b,s,c];
// V[b,c,t] bf16. 512 blocks x 256 threads (4 waves x 32 rows); XCD-pinned;
// 8 bodies of 128 t. K tile [128][64] 3-bit swizzle; V tile [64][128] 4-bit; dbuf 64KB.
__global__ __launch_bounds__(256, 2) void attn(
    const unsigned short* __restrict__ Qt, const unsigned short* __restrict__ Kt,
    const unsigned short* __restrict__ V, float* __restrict__ Out) {
  __shared__ __align__(16) unsigned short lK[2][128 * 64];  // [t][d^swz3], 16KB each
  __shared__ __align__(16) unsigned short lV[2][64 * 128];  // [d][t^swz4], 16KB each
  const int flat = blockIdx.x;
  const int xcd = flat & 7, j = flat >> 3;
  const int pair = xcd * 8 + (j >> 3);
  const int st = j & 7;
  const int b = pair >> 3, h = pair & 7;
  const int tid = threadIdx.x, lane = tid & 63, w = tid >> 6;
  const int lm = lane & 15, lg = lane >> 4;
  const int s0 = st * 128 + w * 32;
  const unsigned short* Qb = Qt + ((long)b * 1024 + s0) * 512 + h * 64;
  const unsigned short* Kb = Kt + (long)b * 1024 * 512 + h * 64;
  const unsigned short* Vb = V + ((long)b * 512 + h * 64) * 1024;

  const int kscol = ((lane & 7) ^ (lane >> 3)) * 8;
  auto stage = [&](int buf, int t0) {
#pragma unroll
    for (int jj = 0; jj < 4; ++jj) {
      int ch = w * 4 + jj;
      int krow = ch * 8 + (lane >> 3);
      __builtin_amdgcn_global_load_lds(GLB_AS(Kb + (long)(t0 + krow) * 512 + kscol),
                                       LDS_AS(&lK[buf][ch * 512]), 16, 0, 0);
      int vrow = ch * 4 + (lane >> 4);
      int vcb = (lane & 15) ^ (vrow & 15);
      __builtin_amdgcn_global_load_lds(GLB_AS(Vb + (long)vrow * 1024 + t0 + vcb * 8),
                                       LDS_AS(&lV[buf][ch * 512]), 16, 0, 0);
    }
  };

  short8 qf[2][2];
#pragma unroll
  for (int si = 0; si < 2; ++si)
#pragma unroll
    for (int kk = 0; kk < 2; ++kk)
      qf[si][kk] = *(const short8*)&Qb[(si * 16 + lm) * 512 + kk * 32 + 8 * lg];

  f32x4 o[2][4] = {};
  float lsum[2] = {};

  stage(0, 0);
  __syncthreads();

#pragma unroll 1
  for (int t = 0; t < 8; ++t) {
    const int cur = t & 1;
    if (t < 7) stage(cur ^ 1, (t + 1) * 128);
    // swapped QK^T: A=K rows (t), B=Q rows (s) -> lane holds P[s=si*16+lm][t chunk]
    f32x4 s[2][8] = {};
    __builtin_amdgcn_s_setprio(1);
#pragma unroll
    for (int tj = 0; tj < 8; ++tj) {
      short8 kf0 = *(const short8*)&lK[cur][(tj * 16 + lm) * 64 + 8 * (lg ^ (lm & 7))];
      short8 kf1 = *(const short8*)&lK[cur][(tj * 16 + lm) * 64 + 8 * ((lg + 4) ^ (lm & 7))];
#pragma unroll
      for (int si = 0; si < 2; ++si) {
        s[si][tj] = mfma16(kf0, qf[si][0], s[si][tj]);
        s[si][tj] = mfma16(kf1, qf[si][1], s[si][tj]);
      }
    }
    __builtin_amdgcn_s_setprio(0);
    // no-max softmax (log2 domain); lane-local row partial sums
#pragma unroll
    for (int si = 0; si < 2; ++si)
#pragma unroll
      for (int tj = 0; tj < 8; ++tj)
#pragma unroll
        for (int r = 0; r < 4; ++r) {
          float p = exp2_hw(s[si][tj][r]);
          s[si][tj][r] = p;
          lsum[si] += p;
        }
    // PV: 4 tk packs (cvt_pk -> permlane32 -> permlane16), 4 MFMAs each per si
#pragma unroll
    for (int tk = 0; tk < 4; ++tk) {
      short8 pa[2];
#pragma unroll
      for (int si = 0; si < 2; ++si) {
        unsigned int X01 = cvtpk(s[si][2 * tk][0], s[si][2 * tk][1]);
        unsigned int X23 = cvtpk(s[si][2 * tk][2], s[si][2 * tk][3]);
        unsigned int Y01 = cvtpk(s[si][2 * tk + 1][0], s[si][2 * tk + 1][1]);
        unsigned int Y23 = cvtpk(s[si][2 * tk + 1][2], s[si][2 * tk + 1][3]);
        asm("v_permlane32_swap_b32 %0, %1" : "+v"(X01), "+v"(Y01));
        asm("v_permlane32_swap_b32 %0, %1" : "+v"(X23), "+v"(Y23));
        asm("v_permlane16_swap_b32 %0, %1" : "+v"(X01), "+v"(Y01));
        asm("v_permlane16_swap_b32 %0, %1" : "+v"(X23), "+v"(Y23));
        u32x4 pw;
        pw[0] = X01;
        pw[1] = X23;
        pw[2] = Y01;
        pw[3] = Y23;
        pa[si] = __builtin_bit_cast(short8, pw);
      }
      __builtin_amdgcn_s_setprio(1);
#pragma unroll
      for (int dj = 0; dj < 4; ++dj) {
        short8 vf = *(const short8*)&lV[cur][(dj * 16 + lm) * 128 + 8 * ((tk * 4 + lg) ^ lm)];
        o[0][dj] = mfma16(pa[0], vf, o[0][dj]);
        o[1][dj] = mfma16(pa[1], vf, o[1][dj]);
      }
      __builtin_amdgcn_s_setprio(0);
    }
    __syncthreads();   // drains staged loads for t+1; protects buffer swap
  }

  // epilogue: reduce row sums across lg (disjoint t-chunks), redistribute, store
  float inv[2][4];
#pragma unroll
  for (int si = 0; si < 2; ++si) {
    float rs = lsum[si];
    rs += __shfl_xor(rs, 16);
    rs += __shfl_xor(rs, 32);           // all lg copies hold total for row lm
#pragma unroll
    for (int r = 0; r < 4; ++r)
      inv[si][r] = 1.0f / __shfl(rs, lg * 4 + r);
  }
#pragma unroll
  for (int si = 0; si < 2; ++si)
#pragma unroll
    for (int dj = 0; dj < 4; ++dj)
#pragma unroll
      for (int r = 0; r < 4; ++r) {
        int srow2 = s0 + si * 16 + lg * 4 + r;
        Out[((long)b * 1024 + srow2) * 512 + h * 64 + dj * 16 + lm] = o[si][dj][r] * inv[si][r];
      }
}

extern "C" void kernel_launch(void* const* d_in, const int* in_sizes, int n_in,
                              void* d_out, int out_size, void* d_ws, size_t ws_size,
                              hipStream_t stream) {
  const float* query = (const float*)d_in[0];
  const float* key   = (const float*)d_in[1];
  const float* value = (const float*)d_in[2];
  const float* wq = (const float*)d_in[3];
  const float* bq = (const float*)d_in[4];
  const float* wk = (const float*)d_in[5];
  const float* bk = (const float*)d_in[6];
  const float* wv = (const float*)d_in[7];
  const float* bv = (const float*)d_in[8];

  unsigned short* ws = (unsigned short*)d_ws;
  const long SC = 1024L * 512;
  unsigned short* W3  = ws;                        // 3 * 512*512 (WQ,WK,WV contiguous)
  unsigned short* QKV = W3 + 3 * 262144;           // 24*SC: Q[0:8], K[8:16], V[16:24]
  unsigned short* QT  = QKV;
  unsigned short* KTm = QKV + 8 * SC;
  unsigned short* VVm = QKV + 16 * SC;

  cast_w3<<<dim3(256, 3), 256, 0, stream>>>(wq, wk, wv, W3);
  gemm_proj<<<768, 256, 0, stream>>>(query, key, value, W3, QKV, bq, bk, bv);
  attn<<<512, 256, 0, stream>>>(QT, KTm, VVm, (float*)d_out);
}

// Round 23
// 71.818 us; speedup vs baseline: 1.7981x; 1.7981x over previous
//
#include <hip/hip_runtime.h>
#include <hip/hip_bf16.h>
#include <stdint.h>

// MultiHeadCrossAttention: B=8, C=512, H=W=32 (S=1024), nh=8, d=64.
// R23 == R22 + __launch_bounds__(256,2) on gemm_proj. R22 post-mortem: missing
//      launch_bounds -> compiler allocated for 1024-thread blocks -> 64-VGPR cap
//      -> vA/vB (64 regs) + acc (64) spilled to scratch: WRITE_SIZE 256MB (vs 25
//      expected), FETCH 153MB, MfmaUtil 0.1%, gemm 125us. Third instance of the
//      register-crush failure mode (R3, R10, R22). One-line fix; static VGPR
//      count ~170 fits the 256 budget at 2 blocks/CU. All else identical.

typedef __attribute__((ext_vector_type(4))) float f32x4;
typedef __attribute__((ext_vector_type(8))) short short8;
typedef __attribute__((ext_vector_type(4))) unsigned int u32x4;

#define GLB_AS(p) ((const __attribute__((address_space(1))) void*)(p))
#define LDS_AS(p) ((__attribute__((address_space(3))) void*)(p))

__device__ __forceinline__ unsigned short f2b(float f) {
  unsigned int x = __builtin_bit_cast(unsigned int, f);
  x = (x + 0x7FFFu + ((x >> 16) & 1u)) >> 16;   // RNE
  return (unsigned short)x;
}

__device__ __forceinline__ float exp2_hw(float x) {
  float r;
  asm("v_exp_f32 %0, %1" : "=v"(r) : "v"(x));
  return r;
}

__device__ __forceinline__ unsigned int cvtpk(float lo, float hi) {
  unsigned int r;
  asm("v_cvt_pk_bf16_f32 %0, %1, %2" : "=v"(r) : "v"(lo), "v"(hi));
  return r;
}

__device__ __forceinline__ f32x4 mfma16(short8 a, short8 b, f32x4 c) {
  return __builtin_amdgcn_mfma_f32_16x16x32_bf16(a, b, c, 0, 0, 0);
}

// ---- prep: 3 weights f32 -> bf16, one small launch ----
__global__ __launch_bounds__(256) void cast_w3(const float* __restrict__ wq,
                                               const float* __restrict__ wk,
                                               const float* __restrict__ wv,
                                               unsigned short* __restrict__ O) {
  const int y = blockIdx.y;
  const float* W = (y == 0) ? wq : ((y == 1) ? wk : wv);
  int i = blockIdx.x * 256 + threadIdx.x;   // 65536 float4 per weight
  float4 v = ((const float4*)W)[i];
  uint2 u;
  u.x = (unsigned)f2b(v.x) | ((unsigned)f2b(v.y) << 16);
  u.y = (unsigned)f2b(v.z) | ((unsigned)f2b(v.w) << 16);
  ((uint2*)(O + (long)y * 262144))[i] = u;
}

// ---- fused projection GEMM: transpose+cast of X folded into staging ----
// bid: batch = bid&7 (pinned to XCD), j = bid>>3: kind = j>>5 (0 Q,1 K,2 V), tile = j&31.
// Q/K: C[s,c] = (X^T . W^T + b) [*scale]; A(X-sourced, swizzled), B=W (gl_lds linear).
// V:   C[c,t] = Wv . X^T + bv;   A=Wv (gl_lds linear), B(X-sourced, swizzled).
__global__ __launch_bounds__(256, 2) void gemm_proj(
    const float* __restrict__ Xq, const float* __restrict__ Xk,
    const float* __restrict__ Xv, const unsigned short* __restrict__ W3,
    unsigned short* __restrict__ QKV, const float* __restrict__ bq,
    const float* __restrict__ bk, const float* __restrict__ bv) {
  __shared__ __align__(16) unsigned short lA[128 * 64];
  __shared__ __align__(16) unsigned short lB[128 * 64];
  const long SC = 1024L * 512;
  const int bid = blockIdx.x;
  const int batch = bid & 7;
  const int j = bid >> 3;
  const int kind = j >> 5, tile = j & 31;
  const bool aFromX = (kind < 2);
  const float* Xsrc = ((kind == 0) ? Xq : ((kind == 1) ? Xk : Xv)) + (long)batch * 512 * 1024;
  const unsigned short* Wsrc = W3 + (long)kind * 262144;
  unsigned short* Cb;
  const float* bias;
  int m0, n0, N, biasN, r0x, wrow0;
  float scale = 1.0f;
  if (aFromX) {
    m0 = (tile >> 2) * 128; n0 = (tile & 3) * 128; N = 512; biasN = 1;
    r0x = m0; wrow0 = n0;
    Cb = QKV + ((long)kind * 8 + batch) * SC;
    bias = kind ? bk : bq;
    if (kind == 0) scale = 0.18033688011112042f;  // 0.125 * log2(e)
  } else {
    m0 = (tile >> 3) * 128; n0 = (tile & 7) * 128; N = 1024; biasN = 0;
    r0x = n0; wrow0 = m0;
    Cb = QKV + (16L + batch) * SC;
    bias = bv;
  }
  unsigned short* lX = aFromX ? lA : lB;   // X-sourced tile (swizzled)
  unsigned short* lW = aFromX ? lB : lA;   // W tile (linear)
  const int tid = threadIdx.x, lane = tid & 63, wid = tid >> 6;
  const int wr = wid >> 1, wc = wid & 1;
  const int lm = lane & 15, lg = lane >> 4;
  const int aX = aFromX ? (lm & 7) : 0;
  const int bX = aFromX ? 0 : (lm & 7);
  // X staging geometry: wave w rows [w*32, w*32+32); oct = c-octet, qd = row-quad
  const int oct = lane & 7, qd = lane >> 3;
  const int xrow = wid * 32 + qd * 4;

  auto loadX = [&](f32x4 (&v)[8], int k0) {
#pragma unroll
    for (int e = 0; e < 8; ++e)
      v[e] = *(const f32x4*)&Xsrc[(long)(k0 + oct * 8 + e) * 1024 + r0x + xrow];
  };
  auto writeX = [&](f32x4 (&v)[8]) {
#pragma unroll
    for (int jj = 0; jj < 4; ++jj) {
      int row = xrow + jj;
      u32x4 pw;
      pw[0] = cvtpk(v[0][jj], v[1][jj]);
      pw[1] = cvtpk(v[2][jj], v[3][jj]);
      pw[2] = cvtpk(v[4][jj], v[5][jj]);
      pw[3] = cvtpk(v[6][jj], v[7][jj]);
      *(u32x4*)&lX[row * 64 + 8 * (oct ^ (row & 7))] = pw;
    }
  };
  auto stageW = [&](int k0) {
#pragma unroll
    for (int ch = wid; ch < 16; ch += 4) {
      int e = ch * 512 + lane * 8;
      int r = e >> 6, cc = e & 63;
      __builtin_amdgcn_global_load_lds(GLB_AS(Wsrc + (long)(wrow0 + r) * 512 + k0 + cc),
                                       LDS_AS(lW + ch * 512), 16, 0, 0);
    }
  };

  f32x4 acc[4][4] = {};
  auto compute = [&]() {
#pragma unroll
    for (int kk = 0; kk < 2; ++kk) {
      short8 af[4], bf[4];
#pragma unroll
      for (int i = 0; i < 4; ++i)
        af[i] = *(const short8*)&lA[(wr * 64 + i * 16 + lm) * 64 + 8 * ((kk * 4 + lg) ^ aX)];
#pragma unroll
      for (int jj = 0; jj < 4; ++jj)
        bf[jj] = *(const short8*)&lB[(wc * 64 + jj * 16 + lm) * 64 + 8 * ((kk * 4 + lg) ^ bX)];
#pragma unroll
      for (int i = 0; i < 4; ++i)
#pragma unroll
        for (int jj = 0; jj < 4; ++jj)
          acc[i][jj] = mfma16(af[i], bf[jj], acc[i][jj]);
    }
  };

  f32x4 vA[8], vB[8];
  loadX(vA, 0);
#pragma unroll 1
  for (int kq = 0; kq < 8; kq += 2) {
    stageW(kq * 64);
    loadX(vB, kq * 64 + 64);          // next k-tile, regs only (no LDS hazard)
    writeX(vA);
    __syncthreads();
    compute();
    __syncthreads();
    stageW(kq * 64 + 64);
    if (kq < 6) loadX(vA, kq * 64 + 128);
    writeX(vB);
    __syncthreads();
    compute();
    __syncthreads();
  }

#pragma unroll
  for (int i = 0; i < 4; ++i)
#pragma unroll
    for (int jj = 0; jj < 4; ++jj)
#pragma unroll
      for (int r = 0; r < 4; ++r) {
        int m = m0 + wr * 64 + i * 16 + lg * 4 + r;
        int n = n0 + wc * 64 + jj * 16 + lm;
        float bvv = biasN ? bias[n] : bias[m];
        Cb[(long)m * N + n] = f2b((acc[i][jj][r] + bvv) * scale);
      }
}

// ---- fused flash attention: KVBLK=128, LDS-staged K/V (swizzled), in-register P ----
// (R18 version, measured best.) Qt[b,s,c] pre-scaled by 0.125*log2e; Kt[b,s,c];
// V[b,c,t] bf16. 512 blocks x 256 threads (4 waves x 32 rows); XCD-pinned;
// 8 bodies of 128 t. K tile [128][64] 3-bit swizzle; V tile [64][128] 4-bit; dbuf 64KB.
__global__ __launch_bounds__(256, 2) void attn(
    const unsigned short* __restrict__ Qt, const unsigned short* __restrict__ Kt,
    const unsigned short* __restrict__ V, float* __restrict__ Out) {
  __shared__ __align__(16) unsigned short lK[2][128 * 64];  // [t][d^swz3], 16KB each
  __shared__ __align__(16) unsigned short lV[2][64 * 128];  // [d][t^swz4], 16KB each
  const int flat = blockIdx.x;
  const int xcd = flat & 7, j = flat >> 3;
  const int pair = xcd * 8 + (j >> 3);
  const int st = j & 7;
  const int b = pair >> 3, h = pair & 7;
  const int tid = threadIdx.x, lane = tid & 63, w = tid >> 6;
  const int lm = lane & 15, lg = lane >> 4;
  const int s0 = st * 128 + w * 32;
  const unsigned short* Qb = Qt + ((long)b * 1024 + s0) * 512 + h * 64;
  const unsigned short* Kb = Kt + (long)b * 1024 * 512 + h * 64;
  const unsigned short* Vb = V + ((long)b * 512 + h * 64) * 1024;

  const int kscol = ((lane & 7) ^ (lane >> 3)) * 8;
  auto stage = [&](int buf, int t0) {
#pragma unroll
    for (int jj = 0; jj < 4; ++jj) {
      int ch = w * 4 + jj;
      int krow = ch * 8 + (lane >> 3);
      __builtin_amdgcn_global_load_lds(GLB_AS(Kb + (long)(t0 + krow) * 512 + kscol),
                                       LDS_AS(&lK[buf][ch * 512]), 16, 0, 0);
      int vrow = ch * 4 + (lane >> 4);
      int vcb = (lane & 15) ^ (vrow & 15);
      __builtin_amdgcn_global_load_lds(GLB_AS(Vb + (long)vrow * 1024 + t0 + vcb * 8),
                                       LDS_AS(&lV[buf][ch * 512]), 16, 0, 0);
    }
  };

  short8 qf[2][2];
#pragma unroll
  for (int si = 0; si < 2; ++si)
#pragma unroll
    for (int kk = 0; kk < 2; ++kk)
      qf[si][kk] = *(const short8*)&Qb[(si * 16 + lm) * 512 + kk * 32 + 8 * lg];

  f32x4 o[2][4] = {};
  float lsum[2] = {};

  stage(0, 0);
  __syncthreads();

#pragma unroll 1
  for (int t = 0; t < 8; ++t) {
    const int cur = t & 1;
    if (t < 7) stage(cur ^ 1, (t + 1) * 128);
    // swapped QK^T: A=K rows (t), B=Q rows (s) -> lane holds P[s=si*16+lm][t chunk]
    f32x4 s[2][8] = {};
    __builtin_amdgcn_s_setprio(1);
#pragma unroll
    for (int tj = 0; tj < 8; ++tj) {
      short8 kf0 = *(const short8*)&lK[cur][(tj * 16 + lm) * 64 + 8 * (lg ^ (lm & 7))];
      short8 kf1 = *(const short8*)&lK[cur][(tj * 16 + lm) * 64 + 8 * ((lg + 4) ^ (lm & 7))];
#pragma unroll
      for (int si = 0; si < 2; ++si) {
        s[si][tj] = mfma16(kf0, qf[si][0], s[si][tj]);
        s[si][tj] = mfma16(kf1, qf[si][1], s[si][tj]);
      }
    }
    __builtin_amdgcn_s_setprio(0);
    // no-max softmax (log2 domain); lane-local row partial sums
#pragma unroll
    for (int si = 0; si < 2; ++si)
#pragma unroll
      for (int tj = 0; tj < 8; ++tj)
#pragma unroll
        for (int r = 0; r < 4; ++r) {
          float p = exp2_hw(s[si][tj][r]);
          s[si][tj][r] = p;
          lsum[si] += p;
        }
    // PV: 4 tk packs (cvt_pk -> permlane32 -> permlane16), 4 MFMAs each per si
#pragma unroll
    for (int tk = 0; tk < 4; ++tk) {
      short8 pa[2];
#pragma unroll
      for (int si = 0; si < 2; ++si) {
        unsigned int X01 = cvtpk(s[si][2 * tk][0], s[si][2 * tk][1]);
        unsigned int X23 = cvtpk(s[si][2 * tk][2], s[si][2 * tk][3]);
        unsigned int Y01 = cvtpk(s[si][2 * tk + 1][0], s[si][2 * tk + 1][1]);
        unsigned int Y23 = cvtpk(s[si][2 * tk + 1][2], s[si][2 * tk + 1][3]);
        asm("v_permlane32_swap_b32 %0, %1" : "+v"(X01), "+v"(Y01));
        asm("v_permlane32_swap_b32 %0, %1" : "+v"(X23), "+v"(Y23));
        asm("v_permlane16_swap_b32 %0, %1" : "+v"(X01), "+v"(Y01));
        asm("v_permlane16_swap_b32 %0, %1" : "+v"(X23), "+v"(Y23));
        u32x4 pw;
        pw[0] = X01;
        pw[1] = X23;
        pw[2] = Y01;
        pw[3] = Y23;
        pa[si] = __builtin_bit_cast(short8, pw);
      }
      __builtin_amdgcn_s_setprio(1);
#pragma unroll
      for (int dj = 0; dj < 4; ++dj) {
        short8 vf = *(const short8*)&lV[cur][(dj * 16 + lm) * 128 + 8 * ((tk * 4 + lg) ^ lm)];
        o[0][dj] = mfma16(pa[0], vf, o[0][dj]);
        o[1][dj] = mfma16(pa[1], vf, o[1][dj]);
      }
      __builtin_amdgcn_s_setprio(0);
    }
    __syncthreads();   // drains staged loads for t+1; protects buffer swap
  }

  // epilogue: reduce row sums across lg (disjoint t-chunks), redistribute, store
  float inv[2][4];
#pragma unroll
  for (int si = 0; si < 2; ++si) {
    float rs = lsum[si];
    rs += __shfl_xor(rs, 16);
    rs += __shfl_xor(rs, 32);           // all lg copies hold total for row lm
#pragma unroll
    for (int r = 0; r < 4; ++r)
      inv[si][r] = 1.0f / __shfl(rs, lg * 4 + r);
  }
#pragma unroll
  for (int si = 0; si < 2; ++si)
#pragma unroll
    for (int dj = 0; dj < 4; ++dj)
#pragma unroll
      for (int r = 0; r < 4; ++r) {
        int srow2 = s0 + si * 16 + lg * 4 + r;
        Out[((long)b * 1024 + srow2) * 512 + h * 64 + dj * 16 + lm] = o[si][dj][r] * inv[si][r];
      }
}

extern "C" void kernel_launch(void* const* d_in, const int* in_sizes, int n_in,
                              void* d_out, int out_size, void* d_ws, size_t ws_size,
                              hipStream_t stream) {
  const float* query = (const float*)d_in[0];
  const float* key   = (const float*)d_in[1];
  const float* value = (const float*)d_in[2];
  const float* wq = (const float*)d_in[3];
  const float* bq = (const float*)d_in[4];
  const float* wk = (const float*)d_in[5];
  const float* bk = (const float*)d_in[6];
  const float* wv = (const float*)d_in[7];
  const float* bv = (const float*)d_in[8];

  unsigned short* ws = (unsigned short*)d_ws;
  const long SC = 1024L * 512;
  unsigned short* W3  = ws;                        // 3 * 512*512 (WQ,WK,WV contiguous)
  unsigned short* QKV = W3 + 3 * 262144;           // 24*SC: Q[0:8], K[8:16], V[16:24]
  unsigned short* QT  = QKV;
  unsigned short* KTm = QKV + 8 * SC;
  unsigned short* VVm = QKV + 16 * SC;

  cast_w3<<<dim3(256, 3), 256, 0, stream>>>(wq, wk, wv, W3);
  gemm_proj<<<768, 256, 0, stream>>>(query, key, value, W3, QKV, bq, bk, bv);
  attn<<<512, 256, 0, stream>>>(QT, KTm, VVm, (float*)d_out);
}

// Round 24
// 64.986 us; speedup vs baseline: 1.9872x; 1.1051x over previous
//
#include <hip/hip_runtime.h>
#include <hip/hip_bf16.h>
#include <stdint.h>

// MultiHeadCrossAttention: B=8, C=512, H=W=32 (S=1024), nh=8, d=64.
// R24 = R18 (measured best, 65.18us) + gemm_proj __launch_bounds__(256,3).
//      R23 post-mortem: fused X-staging fairly tested and REJECTED (46us vs
//      27.5us split; compiler couldn't keep the f32 pipeline in regs, staging
//      serialized on the critical path). Back to the bf16-intermediate split.
//      This round's single delta: lb(256,2)->(256,3) on gemm_proj caps VGPR at
//      170 (m97's identical-shape kernel needs 164) -> 3 blocks/CU -> the
//      768-block grid runs in ONE wave instead of 1.5 (tail eliminated).
//      Budget: attn ~34, gemm 14->~10.5, prep ~13.5, total -> ~61-62us.

typedef __attribute__((ext_vector_type(4))) float f32x4;
typedef __attribute__((ext_vector_type(8))) short short8;
typedef __attribute__((ext_vector_type(4))) unsigned int u32x4;

#define GLB_AS(p) ((const __attribute__((address_space(1))) void*)(p))
#define LDS_AS(p) ((__attribute__((address_space(3))) void*)(p))

__device__ __forceinline__ unsigned short f2b(float f) {
  unsigned int x = __builtin_bit_cast(unsigned int, f);
  x = (x + 0x7FFFu + ((x >> 16) & 1u)) >> 16;   // RNE
  return (unsigned short)x;
}

__device__ __forceinline__ float exp2_hw(float x) {
  float r;
  asm("v_exp_f32 %0, %1" : "=v"(r) : "v"(x));
  return r;
}

__device__ __forceinline__ unsigned int cvtpk(float lo, float hi) {
  unsigned int r;
  asm("v_cvt_pk_bf16_f32 %0, %1, %2" : "=v"(r) : "v"(lo), "v"(hi));
  return r;
}

__device__ __forceinline__ f32x4 mfma16(short8 a, short8 b, f32x4 c) {
  return __builtin_amdgcn_mfma_f32_16x16x32_bf16(a, b, c, 0, 0, 0);
}

// ---- prep: transpose+cast X (z<24) and cast weights (z==24), one launch ----
__global__ __launch_bounds__(256) void prep_all(const float* __restrict__ Xq,
                                                const float* __restrict__ Xk,
                                                const float* __restrict__ Xv,
                                                const float* __restrict__ wq,
                                                const float* __restrict__ wk,
                                                const float* __restrict__ wv,
                                                unsigned short* __restrict__ Xt,
                                                unsigned short* __restrict__ WO) {
  __shared__ float t[64][65];
  const int tid = threadIdx.x;
  if (blockIdx.z == 24) {
    // cast 3 weights: 196608 float4 over 128 blocks x 6 iters
    const int bid = blockIdx.y * 16 + blockIdx.x;
#pragma unroll
    for (int k = 0; k < 6; ++k) {
      int i = bid * 1536 + k * 256 + tid;
      int which = i >> 16, off = i & 65535;
      const float* W = (which == 0) ? wq : ((which == 1) ? wk : wv);
      float4 v = ((const float4*)W)[off];
      uint2 u;
      u.x = (unsigned)f2b(v.x) | ((unsigned)f2b(v.y) << 16);
      u.y = (unsigned)f2b(v.z) | ((unsigned)f2b(v.w) << 16);
      ((uint2*)(WO + (long)which * 262144))[off] = u;
    }
    return;
  }
  const int which = blockIdx.z >> 3, bb = blockIdx.z & 7;
  const float* X = (which == 0) ? Xq : ((which == 1) ? Xk : Xv);
  const int s0 = blockIdx.x * 64, c0 = blockIdx.y * 64;
  const float* Xb = X + (long)bb * 512 * 1024;
  const int col4 = (tid & 15) * 4;
  const int r0 = tid >> 4;
#pragma unroll
  for (int it = 0; it < 4; ++it) {
    int r = r0 + it * 16;
    const float4 v = *(const float4*)&Xb[(long)(c0 + r) * 1024 + s0 + col4];
    t[r][col4 + 0] = v.x; t[r][col4 + 1] = v.y; t[r][col4 + 2] = v.z; t[r][col4 + 3] = v.w;
  }
  __syncthreads();
  const int s = tid >> 2;
  const int cp = (tid & 3) * 16;
  unsigned int u[8];
#pragma unroll
  for (int i = 0; i < 8; ++i) {
    unsigned int lo = f2b(t[cp + 2 * i][s]);
    unsigned int hi = f2b(t[cp + 2 * i + 1][s]);
    u[i] = lo | (hi << 16);
  }
  unsigned short* dst = Xt + (long)which * 8 * 1024 * 512 +
                        ((long)bb * 1024 + s0 + s) * 512 + c0 + cp;
  ((uint4*)dst)[0] = make_uint4(u[0], u[1], u[2], u[3]);
  ((uint4*)dst)[1] = make_uint4(u[4], u[5], u[6], u[7]);
}

// ---- merged Q/K/V projection GEMM, one dispatch (768 blocks = 3 blocks/CU) ----
__global__ __launch_bounds__(256, 3) void gemm_proj(
    const unsigned short* __restrict__ XT, const unsigned short* __restrict__ W3,
    unsigned short* __restrict__ QKV, const float* __restrict__ bq,
    const float* __restrict__ bk, const float* __restrict__ bv) {
  __shared__ __align__(16) unsigned short lA[128 * 64];
  __shared__ __align__(16) unsigned short lB[128 * 64];
  const long SC = 1024L * 512;
  const int bid = blockIdx.x;
  const int kind = bid >> 8;          // 0 Q, 1 K, 2 V
  const int rr = bid & 255;
  const int batch = rr >> 5, tile = rr & 31;
  const unsigned short *Ab, *Bb;
  unsigned short* Cb;
  const float* bias;
  int m0, n0, N, biasN;
  float scale = 1.0f;
  if (kind < 2) {
    m0 = (tile >> 2) * 128; n0 = (tile & 3) * 128; N = 512; biasN = 1;
    Ab = XT + ((long)kind * 8 + batch) * SC;
    Bb = W3 + (long)kind * 262144;
    Cb = QKV + ((long)kind * 8 + batch) * SC;
    bias = kind ? bk : bq;
    if (kind == 0) scale = 0.18033688011112042f;  // 0.125 * log2(e)
  } else {
    m0 = (tile >> 3) * 128; n0 = (tile & 7) * 128; N = 1024; biasN = 0;
    Ab = W3 + 2 * 262144;
    Bb = XT + (16L + batch) * SC;
    Cb = QKV + (16L + batch) * SC;
    bias = bv;
  }
  const int tid = threadIdx.x, lane = tid & 63, wid = tid >> 6;
  const int wr = wid >> 1, wc = wid & 1;
  const int lm = lane & 15, lg = lane >> 4;
  f32x4 acc[4][4] = {};
  for (int k0 = 0; k0 < 512; k0 += 64) {
#pragma unroll
    for (int ch = wid; ch < 16; ch += 4) {
      int e = ch * 512 + lane * 8;
      int r = e >> 6, cc = e & 63;
      __builtin_amdgcn_global_load_lds(GLB_AS(Ab + (long)(m0 + r) * 512 + k0 + cc),
                                       LDS_AS(lA + ch * 512), 16, 0, 0);
      __builtin_amdgcn_global_load_lds(GLB_AS(Bb + (long)(n0 + r) * 512 + k0 + cc),
                                       LDS_AS(lB + ch * 512), 16, 0, 0);
    }
    __syncthreads();
#pragma unroll
    for (int kk = 0; kk < 2; ++kk) {
      short8 af[4], bf[4];
#pragma unroll
      for (int i = 0; i < 4; ++i)
        af[i] = *(const short8*)&lA[(wr * 64 + i * 16 + lm) * 64 + kk * 32 + 8 * lg];
#pragma unroll
      for (int j = 0; j < 4; ++j)
        bf[j] = *(const short8*)&lB[(wc * 64 + j * 16 + lm) * 64 + kk * 32 + 8 * lg];
#pragma unroll
      for (int i = 0; i < 4; ++i)
#pragma unroll
        for (int j = 0; j < 4; ++j)
          acc[i][j] = mfma16(af[i], bf[j], acc[i][j]);
    }
    __syncthreads();
  }
#pragma unroll
  for (int i = 0; i < 4; ++i)
#pragma unroll
    for (int j = 0; j < 4; ++j)
#pragma unroll
      for (int r = 0; r < 4; ++r) {
        int m = m0 + wr * 64 + i * 16 + lg * 4 + r;
        int n = n0 + wc * 64 + j * 16 + lm;
        float bvv = biasN ? bias[n] : bias[m];
        Cb[(long)m * N + n] = f2b((acc[i][j][r] + bvv) * scale);
      }
}

// ---- fused flash attention: KVBLK=128, LDS-staged K/V (swizzled), in-register P ----
// Qt[b,s,c] pre-scaled by 0.125*log2e; Kt[b,s,c]; V[b,c,t] bf16.
// 512 blocks x 256 threads (4 waves x 32 rows); XCD-pinned; 8 bodies of 128 t each.
// K tile [128][64] 3-bit swizzle; V tile [64][128] 4-bit swizzle; dbuf 64KB.
__global__ __launch_bounds__(256, 2) void attn(
    const unsigned short* __restrict__ Qt, const unsigned short* __restrict__ Kt,
    const unsigned short* __restrict__ V, float* __restrict__ Out) {
  __shared__ __align__(16) unsigned short lK[2][128 * 64];  // [t][d^swz3], 16KB each
  __shared__ __align__(16) unsigned short lV[2][64 * 128];  // [d][t^swz4], 16KB each
  const int flat = blockIdx.x;
  const int xcd = flat & 7, j = flat >> 3;
  const int pair = xcd * 8 + (j >> 3);
  const int st = j & 7;
  const int b = pair >> 3, h = pair & 7;
  const int tid = threadIdx.x, lane = tid & 63, w = tid >> 6;
  const int lm = lane & 15, lg = lane >> 4;
  const int s0 = st * 128 + w * 32;
  const unsigned short* Qb = Qt + ((long)b * 1024 + s0) * 512 + h * 64;
  const unsigned short* Kb = Kt + (long)b * 1024 * 512 + h * 64;
  const unsigned short* Vb = V + ((long)b * 512 + h * 64) * 1024;

  const int kscol = ((lane & 7) ^ (lane >> 3)) * 8;
  auto stage = [&](int buf, int t0) {
#pragma unroll
    for (int jj = 0; jj < 4; ++jj) {
      int ch = w * 4 + jj;
      int krow = ch * 8 + (lane >> 3);
      __builtin_amdgcn_global_load_lds(GLB_AS(Kb + (long)(t0 + krow) * 512 + kscol),
                                       LDS_AS(&lK[buf][ch * 512]), 16, 0, 0);
      int vrow = ch * 4 + (lane >> 4);
      int vcb = (lane & 15) ^ (vrow & 15);
      __builtin_amdgcn_global_load_lds(GLB_AS(Vb + (long)vrow * 1024 + t0 + vcb * 8),
                                       LDS_AS(&lV[buf][ch * 512]), 16, 0, 0);
    }
  };

  short8 qf[2][2];
#pragma unroll
  for (int si = 0; si < 2; ++si)
#pragma unroll
    for (int kk = 0; kk < 2; ++kk)
      qf[si][kk] = *(const short8*)&Qb[(si * 16 + lm) * 512 + kk * 32 + 8 * lg];

  f32x4 o[2][4] = {};
  float lsum[2] = {};

  stage(0, 0);
  __syncthreads();

#pragma unroll 1
  for (int t = 0; t < 8; ++t) {
    const int cur = t & 1;
    if (t < 7) stage(cur ^ 1, (t + 1) * 128);
    // swapped QK^T: A=K rows (t), B=Q rows (s) -> lane holds P[s=si*16+lm][t chunk]
    f32x4 s[2][8] = {};
    __builtin_amdgcn_s_setprio(1);
#pragma unroll
    for (int tj = 0; tj < 8; ++tj) {
      short8 kf0 = *(const short8*)&lK[cur][(tj * 16 + lm) * 64 + 8 * (lg ^ (lm & 7))];
      short8 kf1 = *(const short8*)&lK[cur][(tj * 16 + lm) * 64 + 8 * ((lg + 4) ^ (lm & 7))];
#pragma unroll
      for (int si = 0; si < 2; ++si) {
        s[si][tj] = mfma16(kf0, qf[si][0], s[si][tj]);
        s[si][tj] = mfma16(kf1, qf[si][1], s[si][tj]);
      }
    }
    __builtin_amdgcn_s_setprio(0);
    // no-max softmax (log2 domain); lane-local row partial sums
#pragma unroll
    for (int si = 0; si < 2; ++si)
#pragma unroll
      for (int tj = 0; tj < 8; ++tj)
#pragma unroll
        for (int r = 0; r < 4; ++r) {
          float p = exp2_hw(s[si][tj][r]);
          s[si][tj][r] = p;
          lsum[si] += p;
        }
    // PV: 4 tk packs (cvt_pk -> permlane32 -> permlane16), 4 MFMAs each per si
#pragma unroll
    for (int tk = 0; tk < 4; ++tk) {
      short8 pa[2];
#pragma unroll
      for (int si = 0; si < 2; ++si) {
        unsigned int X01 = cvtpk(s[si][2 * tk][0], s[si][2 * tk][1]);
        unsigned int X23 = cvtpk(s[si][2 * tk][2], s[si][2 * tk][3]);
        unsigned int Y01 = cvtpk(s[si][2 * tk + 1][0], s[si][2 * tk + 1][1]);
        unsigned int Y23 = cvtpk(s[si][2 * tk + 1][2], s[si][2 * tk + 1][3]);
        asm("v_permlane32_swap_b32 %0, %1" : "+v"(X01), "+v"(Y01));
        asm("v_permlane32_swap_b32 %0, %1" : "+v"(X23), "+v"(Y23));
        asm("v_permlane16_swap_b32 %0, %1" : "+v"(X01), "+v"(Y01));
        asm("v_permlane16_swap_b32 %0, %1" : "+v"(X23), "+v"(Y23));
        u32x4 pw;
        pw[0] = X01;
        pw[1] = X23;
        pw[2] = Y01;
        pw[3] = Y23;
        pa[si] = __builtin_bit_cast(short8, pw);
      }
      __builtin_amdgcn_s_setprio(1);
#pragma unroll
      for (int dj = 0; dj < 4; ++dj) {
        short8 vf = *(const short8*)&lV[cur][(dj * 16 + lm) * 128 + 8 * ((tk * 4 + lg) ^ lm)];
        o[0][dj] = mfma16(pa[0], vf, o[0][dj]);
        o[1][dj] = mfma16(pa[1], vf, o[1][dj]);
      }
      __builtin_amdgcn_s_setprio(0);
    }
    __syncthreads();   // drains staged loads for t+1; protects buffer swap
  }

  // epilogue: reduce row sums across lg (disjoint t-chunks), redistribute, store
  float inv[2][4];
#pragma unroll
  for (int si = 0; si < 2; ++si) {
    float rs = lsum[si];
    rs += __shfl_xor(rs, 16);
    rs += __shfl_xor(rs, 32);           // all lg copies hold total for row lm
#pragma unroll
    for (int r = 0; r < 4; ++r)
      inv[si][r] = 1.0f / __shfl(rs, lg * 4 + r);
  }
#pragma unroll
  for (int si = 0; si < 2; ++si)
#pragma unroll
    for (int dj = 0; dj < 4; ++dj)
#pragma unroll
      for (int r = 0; r < 4; ++r) {
        int srow2 = s0 + si * 16 + lg * 4 + r;
        Out[((long)b * 1024 + srow2) * 512 + h * 64 + dj * 16 + lm] = o[si][dj][r] * inv[si][r];
      }
}

extern "C" void kernel_launch(void* const* d_in, const int* in_sizes, int n_in,
                              void* d_out, int out_size, void* d_ws, size_t ws_size,
                              hipStream_t stream) {
  const float* query = (const float*)d_in[0];
  const float* key   = (const float*)d_in[1];
  const float* value = (const float*)d_in[2];
  const float* wq = (const float*)d_in[3];
  const float* bq = (const float*)d_in[4];
  const float* wk = (const float*)d_in[5];
  const float* bk = (const float*)d_in[6];
  const float* wv = (const float*)d_in[7];
  const float* bv = (const float*)d_in[8];

  unsigned short* ws = (unsigned short*)d_ws;
  const long SC = 1024L * 512;
  unsigned short* XT  = ws;                        // 3 * 8 * SC (Q,K,V transposed inputs)
  unsigned short* W3  = XT + 24 * SC;              // 3 * 512*512 (WQ,WK,WV contiguous)
  unsigned short* QKV = W3 + 3 * 262144;           // 24*SC: Q[0:8], K[8:16], V[16:24]
  unsigned short* QT  = QKV;
  unsigned short* KTm = QKV + 8 * SC;
  unsigned short* VVm = QKV + 16 * SC;

  prep_all<<<dim3(16, 8, 25), 256, 0, stream>>>(query, key, value, wq, wk, wv, XT, W3);
  gemm_proj<<<768, 256, 0, stream>>>(XT, W3, QKV, bq, bk, bv);
  attn<<<512, 256, 0, stream>>>(QT, KTm, VVm, (float*)d_out);
}

// Round 25
// 63.571 us; speedup vs baseline: 2.0314x; 1.0222x over previous
//
#include <hip/hip_runtime.h>
#include <hip/hip_bf16.h>
#include <stdint.h>

// MultiHeadCrossAttention: B=8, C=512, H=W=32 (S=1024), nh=8, d=64.
// R25 = R24 + XCD-batch pinning for gemm_proj (T1). Block decode remapped from
//      {kind=bid>>8, batch=(bid&255)>>5, tile=bid&31} to {batch=bid&7 (XCD via
//      hw %8 round-robin), kind=(bid>>3)>>5, tile=(bid>>3)&31}: all 96 tiles of
//      batch b run on XCD b -> X-slices (3MB/batch < 4MB L2) stay resident across
//      the x4 A-panel re-reads. R24 post-mortem: lb(256,3) ~neutral (kept).
//      Baseline R24: 64.99us; attn ~34, gemm ~13-14, prep ~13.5.

typedef __attribute__((ext_vector_type(4))) float f32x4;
typedef __attribute__((ext_vector_type(8))) short short8;
typedef __attribute__((ext_vector_type(4))) unsigned int u32x4;

#define GLB_AS(p) ((const __attribute__((address_space(1))) void*)(p))
#define LDS_AS(p) ((__attribute__((address_space(3))) void*)(p))

__device__ __forceinline__ unsigned short f2b(float f) {
  unsigned int x = __builtin_bit_cast(unsigned int, f);
  x = (x + 0x7FFFu + ((x >> 16) & 1u)) >> 16;   // RNE
  return (unsigned short)x;
}

__device__ __forceinline__ float exp2_hw(float x) {
  float r;
  asm("v_exp_f32 %0, %1" : "=v"(r) : "v"(x));
  return r;
}

__device__ __forceinline__ unsigned int cvtpk(float lo, float hi) {
  unsigned int r;
  asm("v_cvt_pk_bf16_f32 %0, %1, %2" : "=v"(r) : "v"(lo), "v"(hi));
  return r;
}

__device__ __forceinline__ f32x4 mfma16(short8 a, short8 b, f32x4 c) {
  return __builtin_amdgcn_mfma_f32_16x16x32_bf16(a, b, c, 0, 0, 0);
}

// ---- prep: transpose+cast X (z<24) and cast weights (z==24), one launch ----
__global__ __launch_bounds__(256) void prep_all(const float* __restrict__ Xq,
                                                const float* __restrict__ Xk,
                                                const float* __restrict__ Xv,
                                                const float* __restrict__ wq,
                                                const float* __restrict__ wk,
                                                const float* __restrict__ wv,
                                                unsigned short* __restrict__ Xt,
                                                unsigned short* __restrict__ WO) {
  __shared__ float t[64][65];
  const int tid = threadIdx.x;
  if (blockIdx.z == 24) {
    // cast 3 weights: 196608 float4 over 128 blocks x 6 iters
    const int bid = blockIdx.y * 16 + blockIdx.x;
#pragma unroll
    for (int k = 0; k < 6; ++k) {
      int i = bid * 1536 + k * 256 + tid;
      int which = i >> 16, off = i & 65535;
      const float* W = (which == 0) ? wq : ((which == 1) ? wk : wv);
      float4 v = ((const float4*)W)[off];
      uint2 u;
      u.x = (unsigned)f2b(v.x) | ((unsigned)f2b(v.y) << 16);
      u.y = (unsigned)f2b(v.z) | ((unsigned)f2b(v.w) << 16);
      ((uint2*)(WO + (long)which * 262144))[off] = u;
    }
    return;
  }
  const int which = blockIdx.z >> 3, bb = blockIdx.z & 7;
  const float* X = (which == 0) ? Xq : ((which == 1) ? Xk : Xv);
  const int s0 = blockIdx.x * 64, c0 = blockIdx.y * 64;
  const float* Xb = X + (long)bb * 512 * 1024;
  const int col4 = (tid & 15) * 4;
  const int r0 = tid >> 4;
#pragma unroll
  for (int it = 0; it < 4; ++it) {
    int r = r0 + it * 16;
    const float4 v = *(const float4*)&Xb[(long)(c0 + r) * 1024 + s0 + col4];
    t[r][col4 + 0] = v.x; t[r][col4 + 1] = v.y; t[r][col4 + 2] = v.z; t[r][col4 + 3] = v.w;
  }
  __syncthreads();
  const int s = tid >> 2;
  const int cp = (tid & 3) * 16;
  unsigned int u[8];
#pragma unroll
  for (int i = 0; i < 8; ++i) {
    unsigned int lo = f2b(t[cp + 2 * i][s]);
    unsigned int hi = f2b(t[cp + 2 * i + 1][s]);
    u[i] = lo | (hi << 16);
  }
  unsigned short* dst = Xt + (long)which * 8 * 1024 * 512 +
                        ((long)bb * 1024 + s0 + s) * 512 + c0 + cp;
  ((uint4*)dst)[0] = make_uint4(u[0], u[1], u[2], u[3]);
  ((uint4*)dst)[1] = make_uint4(u[4], u[5], u[6], u[7]);
}

// ---- merged Q/K/V projection GEMM, one dispatch (768 blocks = 3 blocks/CU) ----
// batch = bid&7 -> pinned to XCD (hw round-robins XCD by blockIdx%8).
__global__ __launch_bounds__(256, 3) void gemm_proj(
    const unsigned short* __restrict__ XT, const unsigned short* __restrict__ W3,
    unsigned short* __restrict__ QKV, const float* __restrict__ bq,
    const float* __restrict__ bk, const float* __restrict__ bv) {
  __shared__ __align__(16) unsigned short lA[128 * 64];
  __shared__ __align__(16) unsigned short lB[128 * 64];
  const long SC = 1024L * 512;
  const int bid = blockIdx.x;
  const int batch = bid & 7;          // XCD-pinned
  const int rest = bid >> 3;          // 0..95
  const int kind = rest >> 5, tile = rest & 31;
  const unsigned short *Ab, *Bb;
  unsigned short* Cb;
  const float* bias;
  int m0, n0, N, biasN;
  float scale = 1.0f;
  if (kind < 2) {
    m0 = (tile >> 2) * 128; n0 = (tile & 3) * 128; N = 512; biasN = 1;
    Ab = XT + ((long)kind * 8 + batch) * SC;
    Bb = W3 + (long)kind * 262144;
    Cb = QKV + ((long)kind * 8 + batch) * SC;
    bias = kind ? bk : bq;
    if (kind == 0) scale = 0.18033688011112042f;  // 0.125 * log2(e)
  } else {
    m0 = (tile >> 3) * 128; n0 = (tile & 7) * 128; N = 1024; biasN = 0;
    Ab = W3 + 2 * 262144;
    Bb = XT + (16L + batch) * SC;
    Cb = QKV + (16L + batch) * SC;
    bias = bv;
  }
  const int tid = threadIdx.x, lane = tid & 63, wid = tid >> 6;
  const int wr = wid >> 1, wc = wid & 1;
  const int lm = lane & 15, lg = lane >> 4;
  f32x4 acc[4][4] = {};
  for (int k0 = 0; k0 < 512; k0 += 64) {
#pragma unroll
    for (int ch = wid; ch < 16; ch += 4) {
      int e = ch * 512 + lane * 8;
      int r = e >> 6, cc = e & 63;
      __builtin_amdgcn_global_load_lds(GLB_AS(Ab + (long)(m0 + r) * 512 + k0 + cc),
                                       LDS_AS(lA + ch * 512), 16, 0, 0);
      __builtin_amdgcn_global_load_lds(GLB_AS(Bb + (long)(n0 + r) * 512 + k0 + cc),
                                       LDS_AS(lB + ch * 512), 16, 0, 0);
    }
    __syncthreads();
#pragma unroll
    for (int kk = 0; kk < 2; ++kk) {
      short8 af[4], bf[4];
#pragma unroll
      for (int i = 0; i < 4; ++i)
        af[i] = *(const short8*)&lA[(wr * 64 + i * 16 + lm) * 64 + kk * 32 + 8 * lg];
#pragma unroll
      for (int j = 0; j < 4; ++j)
        bf[j] = *(const short8*)&lB[(wc * 64 + j * 16 + lm) * 64 + kk * 32 + 8 * lg];
#pragma unroll
      for (int i = 0; i < 4; ++i)
#pragma unroll
        for (int j = 0; j < 4; ++j)
          acc[i][j] = mfma16(af[i], bf[j], acc[i][j]);
    }
    __syncthreads();
  }
#pragma unroll
  for (int i = 0; i < 4; ++i)
#pragma unroll
    for (int j = 0; j < 4; ++j)
#pragma unroll
      for (int r = 0; r < 4; ++r) {
        int m = m0 + wr * 64 + i * 16 + lg * 4 + r;
        int n = n0 + wc * 64 + j * 16 + lm;
        float bvv = biasN ? bias[n] : bias[m];
        Cb[(long)m * N + n] = f2b((acc[i][j][r] + bvv) * scale);
      }
}

// ---- fused flash attention: KVBLK=128, LDS-staged K/V (swizzled), in-register P ----
// Qt[b,s,c] pre-scaled by 0.125*log2e; Kt[b,s,c]; V[b,c,t] bf16.
// 512 blocks x 256 threads (4 waves x 32 rows); XCD-pinned; 8 bodies of 128 t each.
// K tile [128][64] 3-bit swizzle; V tile [64][128] 4-bit swizzle; dbuf 64KB.
__global__ __launch_bounds__(256, 2) void attn(
    const unsigned short* __restrict__ Qt, const unsigned short* __restrict__ Kt,
    const unsigned short* __restrict__ V, float* __restrict__ Out) {
  __shared__ __align__(16) unsigned short lK[2][128 * 64];  // [t][d^swz3], 16KB each
  __shared__ __align__(16) unsigned short lV[2][64 * 128];  // [d][t^swz4], 16KB each
  const int flat = blockIdx.x;
  const int xcd = flat & 7, j = flat >> 3;
  const int pair = xcd * 8 + (j >> 3);
  const int st = j & 7;
  const int b = pair >> 3, h = pair & 7;
  const int tid = threadIdx.x, lane = tid & 63, w = tid >> 6;
  const int lm = lane & 15, lg = lane >> 4;
  const int s0 = st * 128 + w * 32;
  const unsigned short* Qb = Qt + ((long)b * 1024 + s0) * 512 + h * 64;
  const unsigned short* Kb = Kt + (long)b * 1024 * 512 + h * 64;
  const unsigned short* Vb = V + ((long)b * 512 + h * 64) * 1024;

  const int kscol = ((lane & 7) ^ (lane >> 3)) * 8;
  auto stage = [&](int buf, int t0) {
#pragma unroll
    for (int jj = 0; jj < 4; ++jj) {
      int ch = w * 4 + jj;
      int krow = ch * 8 + (lane >> 3);
      __builtin_amdgcn_global_load_lds(GLB_AS(Kb + (long)(t0 + krow) * 512 + kscol),
                                       LDS_AS(&lK[buf][ch * 512]), 16, 0, 0);
      int vrow = ch * 4 + (lane >> 4);
      int vcb = (lane & 15) ^ (vrow & 15);
      __builtin_amdgcn_global_load_lds(GLB_AS(Vb + (long)vrow * 1024 + t0 + vcb * 8),
                                       LDS_AS(&lV[buf][ch * 512]), 16, 0, 0);
    }
  };

  short8 qf[2][2];
#pragma unroll
  for (int si = 0; si < 2; ++si)
#pragma unroll
    for (int kk = 0; kk < 2; ++kk)
      qf[si][kk] = *(const short8*)&Qb[(si * 16 + lm) * 512 + kk * 32 + 8 * lg];

  f32x4 o[2][4] = {};
  float lsum[2] = {};

  stage(0, 0);
  __syncthreads();

#pragma unroll 1
  for (int t = 0; t < 8; ++t) {
    const int cur = t & 1;
    if (t < 7) stage(cur ^ 1, (t + 1) * 128);
    // swapped QK^T: A=K rows (t), B=Q rows (s) -> lane holds P[s=si*16+lm][t chunk]
    f32x4 s[2][8] = {};
    __builtin_amdgcn_s_setprio(1);
#pragma unroll
    for (int tj = 0; tj < 8; ++tj) {
      short8 kf0 = *(const short8*)&lK[cur][(tj * 16 + lm) * 64 + 8 * (lg ^ (lm & 7))];
      short8 kf1 = *(const short8*)&lK[cur][(tj * 16 + lm) * 64 + 8 * ((lg + 4) ^ (lm & 7))];
#pragma unroll
      for (int si = 0; si < 2; ++si) {
        s[si][tj] = mfma16(kf0, qf[si][0], s[si][tj]);
        s[si][tj] = mfma16(kf1, qf[si][1], s[si][tj]);
      }
    }
    __builtin_amdgcn_s_setprio(0);
    // no-max softmax (log2 domain); lane-local row partial sums
#pragma unroll
    for (int si = 0; si < 2; ++si)
#pragma unroll
      for (int tj = 0; tj < 8; ++tj)
#pragma unroll
        for (int r = 0; r < 4; ++r) {
          float p = exp2_hw(s[si][tj][r]);
          s[si][tj][r] = p;
          lsum[si] += p;
        }
    // PV: 4 tk packs (cvt_pk -> permlane32 -> permlane16), 4 MFMAs each per si
#pragma unroll
    for (int tk = 0; tk < 4; ++tk) {
      short8 pa[2];
#pragma unroll
      for (int si = 0; si < 2; ++si) {
        unsigned int X01 = cvtpk(s[si][2 * tk][0], s[si][2 * tk][1]);
        unsigned int X23 = cvtpk(s[si][2 * tk][2], s[si][2 * tk][3]);
        unsigned int Y01 = cvtpk(s[si][2 * tk + 1][0], s[si][2 * tk + 1][1]);
        unsigned int Y23 = cvtpk(s[si][2 * tk + 1][2], s[si][2 * tk + 1][3]);
        asm("v_permlane32_swap_b32 %0, %1" : "+v"(X01), "+v"(Y01));
        asm("v_permlane32_swap_b32 %0, %1" : "+v"(X23), "+v"(Y23));
        asm("v_permlane16_swap_b32 %0, %1" : "+v"(X01), "+v"(Y01));
        asm("v_permlane16_swap_b32 %0, %1" : "+v"(X23), "+v"(Y23));
        u32x4 pw;
        pw[0] = X01;
        pw[1] = X23;
        pw[2] = Y01;
        pw[3] = Y23;
        pa[si] = __builtin_bit_cast(short8, pw);
      }
      __builtin_amdgcn_s_setprio(1);
#pragma unroll
      for (int dj = 0; dj < 4; ++dj) {
        short8 vf = *(const short8*)&lV[cur][(dj * 16 + lm) * 128 + 8 * ((tk * 4 + lg) ^ lm)];
        o[0][dj] = mfma16(pa[0], vf, o[0][dj]);
        o[1][dj] = mfma16(pa[1], vf, o[1][dj]);
      }
      __builtin_amdgcn_s_setprio(0);
    }
    __syncthreads();   // drains staged loads for t+1; protects buffer swap
  }

  // epilogue: reduce row sums across lg (disjoint t-chunks), redistribute, store
  float inv[2][4];
#pragma unroll
  for (int si = 0; si < 2; ++si) {
    float rs = lsum[si];
    rs += __shfl_xor(rs, 16);
    rs += __shfl_xor(rs, 32);           // all lg copies hold total for row lm
#pragma unroll
    for (int r = 0; r < 4; ++r)
      inv[si][r] = 1.0f / __shfl(rs, lg * 4 + r);
  }
#pragma unroll
  for (int si = 0; si < 2; ++si)
#pragma unroll
    for (int dj = 0; dj < 4; ++dj)
#pragma unroll
      for (int r = 0; r < 4; ++r) {
        int srow2 = s0 + si * 16 + lg * 4 + r;
        Out[((long)b * 1024 + srow2) * 512 + h * 64 + dj * 16 + lm] = o[si][dj][r] * inv[si][r];
      }
}

extern "C" void kernel_launch(void* const* d_in, const int* in_sizes, int n_in,
                              void* d_out, int out_size, void* d_ws, size_t ws_size,
                              hipStream_t stream) {
  const float* query = (const float*)d_in[0];
  const float* key   = (const float*)d_in[1];
  const float* value = (const float*)d_in[2];
  const float* wq = (const float*)d_in[3];
  const float* bq = (const float*)d_in[4];
  const float* wk = (const float*)d_in[5];
  const float* bk = (const float*)d_in[6];
  const float* wv = (const float*)d_in[7];
  const float* bv = (const float*)d_in[8];

  unsigned short* ws = (unsigned short*)d_ws;
  const long SC = 1024L * 512;
  unsigned short* XT  = ws;                        // 3 * 8 * SC (Q,K,V transposed inputs)
  unsigned short* W3  = XT + 24 * SC;              // 3 * 512*512 (WQ,WK,WV contiguous)
  unsigned short* QKV = W3 + 3 * 262144;           // 24*SC: Q[0:8], K[8:16], V[16:24]
  unsigned short* QT  = QKV;
  unsigned short* KTm = QKV + 8 * SC;
  unsigned short* VVm = QKV + 16 * SC;

  prep_all<<<dim3(16, 8, 25), 256, 0, stream>>>(query, key, value, wq, wk, wv, XT, W3);
  gemm_proj<<<768, 256, 0, stream>>>(XT, W3, QKV, bq, bk, bv);
  attn<<<512, 256, 0, stream>>>(QT, KTm, VVm, (float*)d_out);
}